// Round 6
// baseline (606.398 us; speedup 1.0000x reference)
//
#include <hip/hip_runtime.h>
#include <math.h>

constexpr int B   = 2;
constexpr int N   = 2048;
constexpr int HID = 768;
constexpr int H   = 12;
constexpr int D   = 64;
constexpr int M   = B * N;
constexpr int QKV_ELEMS = B * H * N * D;   // 3,145,728 elems per tensor

typedef __attribute__((ext_vector_type(8))) short s8v;            // 8 x bf16
typedef __attribute__((ext_vector_type(8))) unsigned short u8v;   // 8 x u16
typedef __attribute__((ext_vector_type(4))) float f4v;            // 4 x f32
typedef unsigned short ushort_t;

__device__ __forceinline__ float bf2f(short u) {
    union { unsigned int i; float f; } v;
    v.i = ((unsigned int)(unsigned short)u) << 16;
    return v.f;
}
__device__ __forceinline__ unsigned short f2bf(float f) {
    union { float f; unsigned int i; } v; v.f = f;
    unsigned int r = v.i + 0x7fff + ((v.i >> 16) & 1);   // RNE
    return (unsigned short)(r >> 16);
}
__device__ __forceinline__ f4v mfma16(s8v a, s8v b, f4v c) {
    return __builtin_amdgcn_mfma_f32_16x16x32_bf16(a, b, c, 0, 0, 0);
}
__device__ __forceinline__ void gl2lds16(const void* g, void* l) {
    __builtin_amdgcn_global_load_lds(
        (const __attribute__((address_space(1))) void*)g,
        (__attribute__((address_space(3))) void*)l, 16, 0, 0);
}
__device__ __forceinline__ u8v cvt8(const float* src) {
    float4 a = *(const float4*)src;
    float4 b = *(const float4*)(src + 4);
    u8v o;
    o[0] = f2bf(a.x); o[1] = f2bf(a.y); o[2] = f2bf(a.z); o[3] = f2bf(a.w);
    o[4] = f2bf(b.x); o[5] = f2bf(b.y); o[6] = f2bf(b.z); o[7] = f2bf(b.w);
    return o;
}

// ---------------------------------------------------------------------------
// Convert everything to bf16 / repack (unchanged).
// ---------------------------------------------------------------------------
constexpr int CVT_C0 = M * HID / 8;
constexpr int CVT_C1 = CVT_C0 + 3 * HID * HID / 8;
constexpr int CVT_C2 = CVT_C1 + H * N * D / 8;
constexpr int CVT_C3 = CVT_C2 + H * N;

__global__ __launch_bounds__(256) void convert_kernel(
    const float* __restrict__ hs,
    const float* __restrict__ Wq, const float* __restrict__ Wk,
    const float* __restrict__ Wv,
    const float* __restrict__ r_emb, const float* __restrict__ r_bias,
    ushort_t* __restrict__ hsb, ushort_t* __restrict__ Wb,
    ushort_t* __restrict__ reb, float* __restrict__ rbt)
{
    const int idx = blockIdx.x * 256 + threadIdx.x;
    if (idx < CVT_C0) {
        *(u8v*)&hsb[(size_t)idx * 8] = cvt8(&hs[(size_t)idx * 8]);
    } else if (idx < CVT_C1) {
        const int j  = idx - CVT_C0;
        const int z  = j / (HID * HID / 8);
        const int jj = j - z * (HID * HID / 8);
        const float* W = (z == 0) ? Wq : ((z == 1) ? Wk : Wv);
        *(u8v*)&Wb[(size_t)z * HID * HID + (size_t)jj * 8] =
            cvt8(&W[(size_t)jj * 8]);
    } else if (idx < CVT_C2) {
        const int k  = idx - CVT_C1;
        const int d0 = (k & 7) * 8;
        const int s  = (k >> 3) & (N - 1);
        const int h  = k >> 14;
        *(u8v*)&reb[(size_t)k * 8] = cvt8(&r_emb[((size_t)s * H + h) * D + d0]);
    } else if (idx < CVT_C3) {
        const int j = idx - CVT_C2;
        const int h = j >> 11;
        const int s = j & (N - 1);
        rbt[j] = r_bias[(size_t)s * H + h];
    }
}

// ---------------------------------------------------------------------------
// QKV projection, bf16 MFMA (unchanged).
// ---------------------------------------------------------------------------
__global__ __launch_bounds__(256) void qkv_mfma_kernel(
    const ushort_t* __restrict__ hsb, const ushort_t* __restrict__ Wb,
    const float* __restrict__ bq, const float* __restrict__ bk,
    const float* __restrict__ bv,
    ushort_t* __restrict__ Qo, ushort_t* __restrict__ Ko,
    ushort_t* __restrict__ Vt)
{
    const int z  = blockIdx.z;
    const int m0 = blockIdx.x * 128;
    const int o0 = blockIdx.y * 128;
    const ushort_t* Wz = Wb + (size_t)z * HID * HID;
    const float* bias = (z == 0) ? bq : ((z == 1) ? bk : bv);

    __shared__ ushort_t Ah[128 * 64];
    __shared__ ushort_t Wh[128 * 64];

    const int t    = threadIdx.x;
    const int lane = t & 63;
    const int w    = t >> 6;
    const int quad = lane >> 4;
    const int col  = lane & 15;
    const int x0   = (w >> 1) * 64;
    const int y0   = (w & 1) * 64;

    const ushort_t* Xs = (z == 2) ? Ah : Wh;
    const ushort_t* Ys = (z == 2) ? Wh : Ah;

    f4v acc[16];
    #pragma unroll
    for (int i = 0; i < 16; i++) acc[i] = (f4v){0.f, 0.f, 0.f, 0.f};

    const int srow = w * 32 + (lane >> 3);
    const int scol = lane & 7;

    for (int k0 = 0; k0 < HID; k0 += 64) {
        __syncthreads();
        #pragma unroll
        for (int e = 0; e < 4; e++) {
            const int row = srow + e * 8;
            const int c8  = scol ^ (row & 7);
            gl2lds16(&hsb[(size_t)(m0 + row) * HID + k0 + c8 * 8],
                     (void*)&Ah[(w * 32 + e * 8) * 64]);
            gl2lds16(&Wz[(size_t)(o0 + row) * HID + k0 + c8 * 8],
                     (void*)&Wh[(w * 32 + e * 8) * 64]);
        }
        __syncthreads();

        #pragma unroll
        for (int ks = 0; ks < 2; ks++) {
            s8v xf[4], yf[4];
            #pragma unroll
            for (int tt = 0; tt < 4; tt++) {
                const int xr  = x0 + tt * 16 + col;
                const int xc8 = (ks * 4 + quad) ^ (xr & 7);
                xf[tt] = *(const s8v*)&Xs[xr * 64 + xc8 * 8];
                const int yr  = y0 + tt * 16 + col;
                const int yc8 = (ks * 4 + quad) ^ (yr & 7);
                yf[tt] = *(const s8v*)&Ys[yr * 64 + yc8 * 8];
            }
            #pragma unroll
            for (int xt = 0; xt < 4; xt++)
                #pragma unroll
                for (int yt = 0; yt < 4; yt++)
                    acc[xt * 4 + yt] = mfma16(xf[xt], yf[yt], acc[xt * 4 + yt]);
        }
    }

    if (z < 2) {
        ushort_t* dst = (z == 0) ? Qo : Ko;
        #pragma unroll
        for (int xt = 0; xt < 4; xt++) {
            const int ob = o0 + x0 + xt * 16 + quad * 4;
            const int h  = ob >> 6;
            const int d0 = ob & 63;
            const float4 bv4 = *(const float4*)&bias[ob];
            #pragma unroll
            for (int yt = 0; yt < 4; yt++) {
                const int m  = m0 + y0 + yt * 16 + col;
                const int bb = m >> 11;
                const int ii = m & (N - 1);
                f4v a = acc[xt * 4 + yt];
                ushort4 pk;
                pk.x = f2bf(a[0] + bv4.x);
                pk.y = f2bf(a[1] + bv4.y);
                pk.z = f2bf(a[2] + bv4.z);
                pk.w = f2bf(a[3] + bv4.w);
                *(ushort4*)&dst[(((size_t)bb * H + h) * N + ii) * D + d0] = pk;
            }
        }
    } else {
        #pragma unroll
        for (int yt = 0; yt < 4; yt++) {
            const int o = o0 + y0 + yt * 16 + col;
            const int h = o >> 6;
            const int d = o & 63;
            const float bs = bias[o];
            #pragma unroll
            for (int xt = 0; xt < 4; xt++) {
                const int m  = m0 + x0 + xt * 16 + quad * 4;
                const int bb = m >> 11;
                const int ib = m & (N - 1);
                f4v a = acc[xt * 4 + yt];
                ushort4 pk;
                pk.x = f2bf(a[0] + bs);
                pk.y = f2bf(a[1] + bs);
                pk.z = f2bf(a[2] + bs);
                pk.w = f2bf(a[3] + bs);
                *(ushort4*)&Vt[(((size_t)bb * H + h) * D + d) * N + ib] = pk;
            }
        }
    }
}

// ---------------------------------------------------------------------------
// Fused relative attention v4: BARRIER-FREE. Each wave owns 16 q rows and is
// fully independent: all MFMA fragments (Q, K, V^T, Res) come straight from
// global (L1/L2-hot); the rel-shift "next row" term is covered by a second
// Sb MFMA set with A = q rows shifted +1 (SbB), so no cross-wave state.
// LDS is wave-private only (SbTA/SbTB diag exchange + Ps transpose): same-
// wave ds ordering via s_waitcnt lgkmcnt(0), zero __syncthreads.
// grid: (N/64, H, B)  block: 256 (4 waves). LDS 34.8 KB -> 4 blocks/CU.
// ---------------------------------------------------------------------------
constexpr int ST = 20;                 // SbT row stride (elems), 40 B rows
constexpr int SBT_W = 80 * ST;         // per-wave SbT elems (80 rows)

__global__ __launch_bounds__(256, 4) void attn_mfma_kernel(
    const ushort_t* __restrict__ Qb, const ushort_t* __restrict__ Kb,
    const ushort_t* __restrict__ Vt, const ushort_t* __restrict__ reb,
    const float* __restrict__ rbt, const float* __restrict__ rwb_g,
    float* __restrict__ out)
{
    const int i0 = blockIdx.x * 64;
    const int h  = blockIdx.y;
    const int b  = blockIdx.z;
    const int bh = b * H + h;

    const ushort_t* Qbh = Qb + (size_t)bh * N * D;
    const ushort_t* Kbh = Kb + (size_t)bh * N * D;
    const ushort_t* Vbh = Vt + (size_t)bh * D * N;   // [d][n]
    const ushort_t* reh = reb + (size_t)h * N * D;   // [s][d]
    const float*    rbh = rbt + (size_t)h * N;

    // LDS: SbTA 4x3200 | SbTB 4x3200 | Ps 4x16x72  = 34816 B total
    __shared__ __align__(16) char smem[34816];

    const int t    = threadIdx.x;
    const int lane = t & 63;
    const int w    = t >> 6;
    const int quad = lane >> 4;
    const int col  = lane & 15;

    ushort_t* SbTA = (ushort_t*)smem + w * SBT_W;
    ushort_t* SbTB = (ushort_t*)(smem + 12800) + w * SBT_W;
    ushort_t (*Ps)[72] = (ushort_t(*)[72])(smem + 25600) + w * 16;

    // ---- init: Q fragments straight from global ----
    const int R0 = i0 + 16 * w;
    s8v qr[2], qbf[2], qw[2];
    {
        const int r1 = min(R0 + 1 + col, N - 1);   // clamped (unused at edge)
        #pragma unroll
        for (int ks = 0; ks < 2; ks++) {
            qr[ks]  = *(const s8v*)&Qbh[(size_t)(R0 + col) * D + ks * 32 + quad * 8];
            qbf[ks] = *(const s8v*)&Qbh[(size_t)r1 * D + ks * 32 + quad * 8];
            float4 ra = *(const float4*)&rwb_g[h * D + ks * 32 + quad * 8];
            float4 rb4 = *(const float4*)&rwb_g[h * D + ks * 32 + quad * 8 + 4];
            const float rv[8] = {ra.x, ra.y, ra.z, ra.w, rb4.x, rb4.y, rb4.z, rb4.w};
            s8v qq;
            #pragma unroll
            for (int j = 0; j < 8; j++)
                qq[j] = (short)f2bf(bf2f(qr[ks][j]) + rv[j]);
            qw[ks] = qq;
        }
    }

    f4v Oacc[4];
    #pragma unroll
    for (int dt = 0; dt < 4; dt++) Oacc[dt] = (f4v){0.f, 0.f, 0.f, 0.f};
    float lacc[4] = {0.f, 0.f, 0.f, 0.f};

    // Res source row: tv = j0 + cres + tt*16; wrap <0 +N; clamp >=0.
    const int cres = -i0 - 17 - 16 * w + col;
    // exp(x*0.125) == exp2(x * 0.125*log2(e))
    const float ESC = 0.18033688011112042f;

    #pragma unroll 1
    for (int s = 0; s < 32; ++s) {
        const int j0 = s * 64;

        // ---- K fragments (global) + AC ----
        s8v kb[4][2];
        #pragma unroll
        for (int tile = 0; tile < 4; tile++)
            #pragma unroll
            for (int ks = 0; ks < 2; ks++)
                kb[tile][ks] = *(const s8v*)
                    &Kbh[(size_t)(j0 + tile * 16 + col) * D + ks * 32 + quad * 8];

        // ---- Res fragments + rb (global) ----
        s8v rf[5][2];
        float rbv[5];
        #pragma unroll
        for (int tt = 0; tt < 5; tt++) {
            int tv = j0 + cres + tt * 16;
            if (tv < 0) tv += N;
            const int src = tv < 0 ? 0 : tv;
            #pragma unroll
            for (int ks = 0; ks < 2; ks++)
                rf[tt][ks] = *(const s8v*)&reh[(size_t)src * D + ks * 32 + quad * 8];
            rbv[tt] = rbh[src];
        }

        f4v acc[4];
        #pragma unroll
        for (int tile = 0; tile < 4; tile++) {
            acc[tile] = (f4v){0.f, 0.f, 0.f, 0.f};
            #pragma unroll
            for (int ks = 0; ks < 2; ks++)
                acc[tile] = mfma16(qw[ks], kb[tile][ks], acc[tile]);
        }

        // ---- SbA (rows R0..R0+15) and SbB (rows R0+1..R0+16) ----
        #pragma unroll
        for (int tt = 0; tt < 5; tt++) {
            f4v sa = (f4v){0.f, 0.f, 0.f, 0.f};
            f4v sb = (f4v){0.f, 0.f, 0.f, 0.f};
            #pragma unroll
            for (int ks = 0; ks < 2; ks++) {
                sa = mfma16(qr[ks],  rf[tt][ks], sa);
                sb = mfma16(qbf[ks], rf[tt][ks], sb);
            }
            ushort4 pa, pb;
            pa.x = f2bf(sa[0] + rbv[tt]); pa.y = f2bf(sa[1] + rbv[tt]);
            pa.z = f2bf(sa[2] + rbv[tt]); pa.w = f2bf(sa[3] + rbv[tt]);
            pb.x = f2bf(sb[0] + rbv[tt]); pb.y = f2bf(sb[1] + rbv[tt]);
            pb.z = f2bf(sb[2] + rbv[tt]); pb.w = f2bf(sb[3] + rbv[tt]);
            const int ro = (tt * 16 + col) * ST + quad * 4;
            *(ushort4*)&SbTA[ro] = pa;      // ds_write_b64
            *(ushort4*)&SbTB[ro] = pb;
        }

        // ---- V fragments (global, issued early to overlap gather) ----
        __asm__ volatile("s_waitcnt lgkmcnt(0)" ::: "memory");
        s8v vfr[4][2];
        #pragma unroll
        for (int dt = 0; dt < 4; dt++)
            #pragma unroll
            for (int ks = 0; ks < 2; ks++)
                vfr[dt][ks] = *(const s8v*)
                    &Vbh[(size_t)(dt * 16 + col) * N + j0 + ks * 32 + quad * 8];

        // ---- gather (rel_shift) + no-max softmax ----
        const int T0 = j0 - i0 - 16 * w;
        float p[4][4];
        #pragma unroll
        for (int tile = 0; tile < 4; tile++) {
            const int cp = tile * 16 + col;
            #pragma unroll
            for (int reg = 0; reg < 4; reg++) {
                const int rl   = quad * 4 + reg;
                const int trel = T0 + cp - rl;
                const int selb = (trel >= 2);
                const ushort_t* sbase = selb ? SbTB : SbTA;
                const int ur = cp - rl + 16 - selb;    // always in [0,79]
                float bd = bf2f((short)sbase[ur * ST + rl]);
                if (trel == 1) bd = 0.f;
                const float e = __builtin_exp2f((acc[tile][reg] + bd) * ESC);
                p[tile][reg] = e;
                lacc[reg] += e;
            }
        }

        // ---- P -> wave-private Ps, PV ----
        #pragma unroll
        for (int tile = 0; tile < 4; tile++)
            #pragma unroll
            for (int reg = 0; reg < 4; reg++)
                Ps[quad * 4 + reg][tile * 16 + col] = f2bf(p[tile][reg]);
        __asm__ volatile("s_waitcnt lgkmcnt(0)" ::: "memory");
        s8v pf[2];
        #pragma unroll
        for (int ks = 0; ks < 2; ks++)
            pf[ks] = *(s8v*)&Ps[col][ks * 32 + quad * 8];
        #pragma unroll
        for (int dt = 0; dt < 4; dt++)
            #pragma unroll
            for (int ks = 0; ks < 2; ks++)
                Oacc[dt] = mfma16(pf[ks], vfr[dt][ks], Oacc[dt]);
    }

    // ---- final l reduction (16 lanes per row) + epilogue ----
    #pragma unroll
    for (int reg = 0; reg < 4; reg++) {
        #pragma unroll
        for (int msk = 1; msk < 16; msk <<= 1)
            lacc[reg] += __shfl_xor(lacc[reg], msk, 64);
    }
    #pragma unroll
    for (int reg = 0; reg < 4; reg++) {
        const float inv = 1.f / lacc[reg];
        const int row = i0 + 16 * w + quad * 4 + reg;
        const size_t base = ((size_t)b * N + row) * HID + h * D;
        #pragma unroll
        for (int dt = 0; dt < 4; dt++)
            out[base + dt * 16 + col] = Oacc[dt][reg] * inv;
    }
}

// ---------------------------------------------------------------------------
extern "C" void kernel_launch(void* const* d_in, const int* in_sizes, int n_in,
                              void* d_out, int out_size, void* d_ws, size_t ws_size,
                              hipStream_t stream)
{
    (void)in_sizes; (void)n_in; (void)out_size; (void)ws_size;
    const float* hs   = (const float*)d_in[0];
    const float* remb = (const float*)d_in[1];
    const float* rwb  = (const float*)d_in[2];
    const float* rb   = (const float*)d_in[3];
    const float* Wq   = (const float*)d_in[4];
    const float* bq   = (const float*)d_in[5];
    const float* Wk   = (const float*)d_in[6];
    const float* bk   = (const float*)d_in[7];
    const float* Wv   = (const float*)d_in[8];
    const float* bv   = (const float*)d_in[9];
    float* out = (float*)d_out;

    ushort_t* Qb  = (ushort_t*)d_ws;
    ushort_t* Kb  = Qb + QKV_ELEMS;
    ushort_t* Vt  = Kb + QKV_ELEMS;
    ushort_t* reb = Vt + QKV_ELEMS;
    float*    rbt = (float*)(reb + H * N * D);
    ushort_t* hsb = (ushort_t*)(rbt + H * N);
    ushort_t* Wb  = hsb + (size_t)M * HID;

    convert_kernel<<<CVT_C3 / 256, 256, 0, stream>>>(
        hs, Wq, Wk, Wv, remb, rb, hsb, Wb, reb, rbt);
    qkv_mfma_kernel<<<dim3(M / 128, HID / 128, 3), 256, 0, stream>>>(
        hsb, Wb, bq, bk, bv, Qb, Kb, Vt);
    attn_mfma_kernel<<<dim3(N / 64, H, B), 256, 0, stream>>>(
        Qb, Kb, Vt, reb, rbt, rwb, out);
}

// Round 7
// 317.441 us; speedup vs baseline: 1.9103x; 1.9103x over previous
//
#include <hip/hip_runtime.h>
#include <math.h>

constexpr int B   = 2;
constexpr int N   = 2048;
constexpr int HID = 768;
constexpr int H   = 12;
constexpr int D   = 64;
constexpr int M   = B * N;
constexpr int QKV_ELEMS = B * H * N * D;   // 3,145,728 elems per tensor

typedef __attribute__((ext_vector_type(8))) short s8v;            // 8 x bf16
typedef __attribute__((ext_vector_type(8))) unsigned short u8v;   // 8 x u16
typedef __attribute__((ext_vector_type(4))) float f4v;            // 4 x f32
typedef unsigned short ushort_t;

__device__ __forceinline__ float bf2f(short u) {
    union { unsigned int i; float f; } v;
    v.i = ((unsigned int)(unsigned short)u) << 16;
    return v.f;
}
__device__ __forceinline__ unsigned short f2bf(float f) {
    union { float f; unsigned int i; } v; v.f = f;
    unsigned int r = v.i + 0x7fff + ((v.i >> 16) & 1);   // RNE
    return (unsigned short)(r >> 16);
}
__device__ __forceinline__ f4v mfma16(s8v a, s8v b, f4v c) {
    return __builtin_amdgcn_mfma_f32_16x16x32_bf16(a, b, c, 0, 0, 0);
}
__device__ __forceinline__ void gl2lds16(const void* g, void* l) {
    __builtin_amdgcn_global_load_lds(
        (const __attribute__((address_space(1))) void*)g,
        (__attribute__((address_space(3))) void*)l, 16, 0, 0);
}
__device__ __forceinline__ u8v cvt8(const float* src) {
    float4 a = *(const float4*)src;
    float4 b = *(const float4*)(src + 4);
    u8v o;
    o[0] = f2bf(a.x); o[1] = f2bf(a.y); o[2] = f2bf(a.z); o[3] = f2bf(a.w);
    o[4] = f2bf(b.x); o[5] = f2bf(b.y); o[6] = f2bf(b.z); o[7] = f2bf(b.w);
    return o;
}
__device__ __forceinline__ int clampsrc(int tv) {
    int src = (tv < 0) ? tv + N : tv;
    return (src < 0) ? 0 : ((src > N - 1) ? N - 1 : src);
}

// ---------------------------------------------------------------------------
// Convert everything to bf16 / repack (unchanged).
// ---------------------------------------------------------------------------
constexpr int CVT_C0 = M * HID / 8;
constexpr int CVT_C1 = CVT_C0 + 3 * HID * HID / 8;
constexpr int CVT_C2 = CVT_C1 + H * N * D / 8;
constexpr int CVT_C3 = CVT_C2 + H * N;

__global__ __launch_bounds__(256) void convert_kernel(
    const float* __restrict__ hs,
    const float* __restrict__ Wq, const float* __restrict__ Wk,
    const float* __restrict__ Wv,
    const float* __restrict__ r_emb, const float* __restrict__ r_bias,
    ushort_t* __restrict__ hsb, ushort_t* __restrict__ Wb,
    ushort_t* __restrict__ reb, float* __restrict__ rbt)
{
    const int idx = blockIdx.x * 256 + threadIdx.x;
    if (idx < CVT_C0) {
        *(u8v*)&hsb[(size_t)idx * 8] = cvt8(&hs[(size_t)idx * 8]);
    } else if (idx < CVT_C1) {
        const int j  = idx - CVT_C0;
        const int z  = j / (HID * HID / 8);
        const int jj = j - z * (HID * HID / 8);
        const float* W = (z == 0) ? Wq : ((z == 1) ? Wk : Wv);
        *(u8v*)&Wb[(size_t)z * HID * HID + (size_t)jj * 8] =
            cvt8(&W[(size_t)jj * 8]);
    } else if (idx < CVT_C2) {
        const int k  = idx - CVT_C1;
        const int d0 = (k & 7) * 8;
        const int s  = (k >> 3) & (N - 1);
        const int h  = k >> 14;
        *(u8v*)&reb[(size_t)k * 8] = cvt8(&r_emb[((size_t)s * H + h) * D + d0]);
    } else if (idx < CVT_C3) {
        const int j = idx - CVT_C2;
        const int h = j >> 11;
        const int s = j & (N - 1);
        rbt[j] = r_bias[(size_t)s * H + h];
    }
}

// ---------------------------------------------------------------------------
// QKV projection, bf16 MFMA (unchanged).
// ---------------------------------------------------------------------------
__global__ __launch_bounds__(256) void qkv_mfma_kernel(
    const ushort_t* __restrict__ hsb, const ushort_t* __restrict__ Wb,
    const float* __restrict__ bq, const float* __restrict__ bk,
    const float* __restrict__ bv,
    ushort_t* __restrict__ Qo, ushort_t* __restrict__ Ko,
    ushort_t* __restrict__ Vt)
{
    const int z  = blockIdx.z;
    const int m0 = blockIdx.x * 128;
    const int o0 = blockIdx.y * 128;
    const ushort_t* Wz = Wb + (size_t)z * HID * HID;
    const float* bias = (z == 0) ? bq : ((z == 1) ? bk : bv);

    __shared__ ushort_t Ah[128 * 64];
    __shared__ ushort_t Wh[128 * 64];

    const int t    = threadIdx.x;
    const int lane = t & 63;
    const int w    = t >> 6;
    const int quad = lane >> 4;
    const int col  = lane & 15;
    const int x0   = (w >> 1) * 64;
    const int y0   = (w & 1) * 64;

    const ushort_t* Xs = (z == 2) ? Ah : Wh;
    const ushort_t* Ys = (z == 2) ? Wh : Ah;

    f4v acc[16];
    #pragma unroll
    for (int i = 0; i < 16; i++) acc[i] = (f4v){0.f, 0.f, 0.f, 0.f};

    const int srow = w * 32 + (lane >> 3);
    const int scol = lane & 7;

    for (int k0 = 0; k0 < HID; k0 += 64) {
        __syncthreads();
        #pragma unroll
        for (int e = 0; e < 4; e++) {
            const int row = srow + e * 8;
            const int c8  = scol ^ (row & 7);
            gl2lds16(&hsb[(size_t)(m0 + row) * HID + k0 + c8 * 8],
                     (void*)&Ah[(w * 32 + e * 8) * 64]);
            gl2lds16(&Wz[(size_t)(o0 + row) * HID + k0 + c8 * 8],
                     (void*)&Wh[(w * 32 + e * 8) * 64]);
        }
        __syncthreads();

        #pragma unroll
        for (int ks = 0; ks < 2; ks++) {
            s8v xf[4], yf[4];
            #pragma unroll
            for (int tt = 0; tt < 4; tt++) {
                const int xr  = x0 + tt * 16 + col;
                const int xc8 = (ks * 4 + quad) ^ (xr & 7);
                xf[tt] = *(const s8v*)&Xs[xr * 64 + xc8 * 8];
                const int yr  = y0 + tt * 16 + col;
                const int yc8 = (ks * 4 + quad) ^ (yr & 7);
                yf[tt] = *(const s8v*)&Ys[yr * 64 + yc8 * 8];
            }
            #pragma unroll
            for (int xt = 0; xt < 4; xt++)
                #pragma unroll
                for (int yt = 0; yt < 4; yt++)
                    acc[xt * 4 + yt] = mfma16(xf[xt], yf[yt], acc[xt * 4 + yt]);
        }
    }

    if (z < 2) {
        ushort_t* dst = (z == 0) ? Qo : Ko;
        #pragma unroll
        for (int xt = 0; xt < 4; xt++) {
            const int ob = o0 + x0 + xt * 16 + quad * 4;
            const int h  = ob >> 6;
            const int d0 = ob & 63;
            const float4 bv4 = *(const float4*)&bias[ob];
            #pragma unroll
            for (int yt = 0; yt < 4; yt++) {
                const int m  = m0 + y0 + yt * 16 + col;
                const int bb = m >> 11;
                const int ii = m & (N - 1);
                f4v a = acc[xt * 4 + yt];
                ushort4 pk;
                pk.x = f2bf(a[0] + bv4.x);
                pk.y = f2bf(a[1] + bv4.y);
                pk.z = f2bf(a[2] + bv4.z);
                pk.w = f2bf(a[3] + bv4.w);
                *(ushort4*)&dst[(((size_t)bb * H + h) * N + ii) * D + d0] = pk;
            }
        }
    } else {
        #pragma unroll
        for (int yt = 0; yt < 4; yt++) {
            const int o = o0 + y0 + yt * 16 + col;
            const int h = o >> 6;
            const int d = o & 63;
            const float bs = bias[o];
            #pragma unroll
            for (int xt = 0; xt < 4; xt++) {
                const int m  = m0 + x0 + xt * 16 + quad * 4;
                const int bb = m >> 11;
                const int ib = m & (N - 1);
                f4v a = acc[xt * 4 + yt];
                ushort4 pk;
                pk.x = f2bf(a[0] + bs);
                pk.y = f2bf(a[1] + bs);
                pk.z = f2bf(a[2] + bs);
                pk.w = f2bf(a[3] + bs);
                *(ushort4*)&Vt[(((size_t)bb * H + h) * D + d) * N + ib] = pk;
            }
        }
    }
}

// ---------------------------------------------------------------------------
// Fused relative attention v5 == v3 structure (V direct from global, 50.4 KB
// LDS -> 3 blocks/CU, 2 barriers/tile) but with PLAIN __launch_bounds__(256):
// rounds 5/6 proved any VGPR squeeze (84/64) causes scratch spills that
// dominate everything. Let the allocator take ~100-120 regs, no spills.
// grid: (N/64, H, B)  block: 256 (4 waves), wave w owns q rows 16w..16w+15.
// ---------------------------------------------------------------------------
__global__ __launch_bounds__(256) void attn_mfma_kernel(
    const ushort_t* __restrict__ Qb, const ushort_t* __restrict__ Kb,
    const ushort_t* __restrict__ Vt, const ushort_t* __restrict__ reb,
    const float* __restrict__ rbt, const float* __restrict__ rwb_g,
    float* __restrict__ out)
{
    const int i0 = blockIdx.x * 64;
    const int h  = blockIdx.y;
    const int b  = blockIdx.z;
    const int bh = b * H + h;

    const ushort_t* Qbh = Qb + (size_t)bh * N * D;
    const ushort_t* Kbh = Kb + (size_t)bh * N * D;
    const ushort_t* Vbh = Vt + (size_t)bh * D * N;   // [d][n]
    const ushort_t* reh = reb + (size_t)h * N * D;   // [s][d]
    const float*    rbh = rbt + (size_t)h * N;

    // LDS: Ks 9216 | Res 18432 | SbT 13056 | Rb 512 | QL/Ps 9216 = 50432
    __shared__ __align__(16) char smem[50432];
    ushort_t (*Ks)[72]  = (ushort_t(*)[72])(smem + 0);       // 64x72 [key][d]
    ushort_t (*Res)[72] = (ushort_t(*)[72])(smem + 9216);    // 128x72 ring
    ushort_t (*SbT)[68] = (ushort_t(*)[68])(smem + 27648);   // 96x68 diagonal
    float*    Rb        = (float*)(smem + 40704);            // 128 ring
    ushort_t (*QL)[72]  = (ushort_t(*)[72])(smem + 41216);   // init only
    ushort_t (*PsAll)[72] = (ushort_t(*)[72])(smem + 41216); // aliases QL

    const int t    = threadIdx.x;
    const int lane = t & 63;
    const int w    = t >> 6;
    const int quad = lane >> 4;
    const int col  = lane & 15;
    ushort_t (*Ps)[72] = PsAll + w * 16;

    // ---- init: Q rows into QL; q64 row into regs ----
    #pragma unroll
    for (int e = 0; e < 2; e++) {
        const int idx = t + e * 256;
        const int r   = idx >> 3;
        const int d8  = (idx & 7) * 8;
        *(s8v*)&QL[r][d8] = *(const s8v*)&Qbh[(size_t)(i0 + r) * D + d8];
    }
    const int sub = t & 3;             // row-64 dot: 16-d chunk index
    s8v q64a = {0,0,0,0,0,0,0,0}, q64b = {0,0,0,0,0,0,0,0};
    if (i0 + 64 < N) {
        q64a = *(const s8v*)&Qbh[(size_t)(i0 + 64) * D + sub * 16];
        q64b = *(const s8v*)&Qbh[(size_t)(i0 + 64) * D + sub * 16 + 8];
    }
    __syncthreads();

    s8v qr[2], qw[2];
    #pragma unroll
    for (int ks = 0; ks < 2; ks++) {
        qr[ks] = *(s8v*)&QL[16 * w + col][ks * 32 + quad * 8];
        float4 r0 = *(const float4*)&rwb_g[h * D + ks * 32 + quad * 8];
        float4 r1 = *(const float4*)&rwb_g[h * D + ks * 32 + quad * 8 + 4];
        const float rv[8] = {r0.x, r0.y, r0.z, r0.w, r1.x, r1.y, r1.z, r1.w};
        s8v qq;
        #pragma unroll
        for (int j = 0; j < 8; j++)
            qq[j] = (short)f2bf(bf2f(qr[ks][j]) + rv[j]);
        qw[ks] = qq;
    }
    __syncthreads();   // QL fully consumed (Ps aliases it)

    // ---- prologue: stage tile 0 (K, full 128-row Res window, Rb) ----
    {
        #pragma unroll
        for (int e = 0; e < 2; e++) {
            const int idx = t + e * 256;
            const int r   = idx >> 3;
            const int d8  = (idx & 7) * 8;
            *(s8v*)&Ks[r][d8] = *(const s8v*)&Kbh[(size_t)r * D + d8];
        }
        #pragma unroll
        for (int e = 0; e < 4; e++) {
            const int idx = t + e * 256;
            const int u   = idx >> 3;
            const int d8  = (idx & 7) * 8;
            const int src = clampsrc(u - i0 - 65);
            *(s8v*)&Res[u][d8] = *(const s8v*)&reh[(size_t)src * D + d8];
        }
        if (t < 128) Rb[t] = rbh[clampsrc(t - i0 - 65)];
    }

    f4v Oacc[4];
    #pragma unroll
    for (int dt = 0; dt < 4; dt++) Oacc[dt] = (f4v){0.f, 0.f, 0.f, 0.f};
    float lacc[4] = {0.f, 0.f, 0.f, 0.f};

    const int u0w  = 48 - 16 * w;
    const int u64  = 16 * w + (lane >> 2);   // row-64 dot: this thread's u
    int off = 0;                              // ring offset = 64*s & 127

    for (int s = 0; s < 32; ++s) {
        const int j0 = s * 64;
        __syncthreads();   // [A] staged tile s visible; prior reads all done

        // ---- V fragments for tile s: direct global loads (L2-hot) ----
        s8v vfr[4][2];
        #pragma unroll
        for (int dt = 0; dt < 4; dt++)
            #pragma unroll
            for (int ks = 0; ks < 2; ks++)
                vfr[dt][ks] = *(const s8v*)
                    &Vbh[(size_t)(dt * 16 + col) * N + j0 + ks * 32 + quad * 8];

        // ---- prefetch tile s+1 staging into regs ----
        s8v pk[2], pr[2];
        float prb = 0.f;
        const int jn = j0 + 64;
        if (s < 31) {
            #pragma unroll
            for (int e = 0; e < 2; e++) {
                const int idx = t + e * 256;
                const int r   = idx >> 3;
                const int d8  = (idx & 7) * 8;
                pk[e] = *(const s8v*)&Kbh[(size_t)(jn + r) * D + d8];
                const int src = clampsrc(jn - i0 - 1 + r);
                pr[e] = *(const s8v*)&reh[(size_t)src * D + d8];
            }
            if (t < 64) prb = rbh[clampsrc(jn - i0 - 1 + t)];
        }

        // ---- AC: Qw @ K^T ----
        f4v acc[4];
        #pragma unroll
        for (int tile = 0; tile < 4; tile++) {
            acc[tile] = (f4v){0.f, 0.f, 0.f, 0.f};
            #pragma unroll
            for (int ks = 0; ks < 2; ks++) {
                s8v kb = *(s8v*)&Ks[tile * 16 + col][ks * 32 + quad * 8];
                acc[tile] = mfma16(qw[ks], kb, acc[tile]);
            }
        }
        // ---- BD product -> diagonal SbT (ring-indexed Res reads) ----
        #pragma unroll
        for (int tt = 0; tt < 5; tt++) {
            const int u = u0w + tt * 16 + col;
            f4v sb = (f4v){0.f, 0.f, 0.f, 0.f};
            #pragma unroll
            for (int ks = 0; ks < 2; ks++) {
                s8v rb8 = *(s8v*)&Res[(u + off) & 127][ks * 32 + quad * 8];
                sb = mfma16(qr[ks], rb8, sb);
            }
            const float rbv = Rb[(u + off) & 127];
            #pragma unroll
            for (int reg = 0; reg < 4; reg++) {
                const int rho = 16 * w + quad * 4 + reg;
                SbT[tt * 16 + col + quad * 4 + reg][rho] = f2bf(sb[reg] + rbv);
            }
        }
        // ---- row 64 (distributed): SbT[u+16][64] = q64 . res(u) + rb ----
        {
            float part = 0.f;
            const int rp = (u64 + off) & 127;
            s8v r0 = *(s8v*)&Res[rp][sub * 16];
            s8v r1 = *(s8v*)&Res[rp][sub * 16 + 8];
            #pragma unroll
            for (int j = 0; j < 8; j++) {
                part += bf2f(q64a[j]) * bf2f(r0[j]);
                part += bf2f(q64b[j]) * bf2f(r1[j]);
            }
            part += __shfl_xor(part, 1, 64);
            part += __shfl_xor(part, 2, 64);
            if (sub == 0)
                SbT[u64 + 16][64] = f2bf(part + Rb[rp]);
        }
        __syncthreads();   // [B] SbT complete; all Ks/Res/Rb reads done

        // ---- gather (rel_shift) + no-max softmax ----
        float p[4][4];
        const int rbase = 16 * w + quad * 4;
        #pragma unroll
        for (int tile = 0; tile < 4; tile++) {
            const int cr   = tile * 16 + col + 16;   // SbT row = cp + 16
            ushort4 q4a = *(ushort4*)&SbT[cr][rbase];
            ushort_t b4 = SbT[cr][rbase + 4];
            const int tr0 = (j0 + tile * 16 + col) - (i0 + rbase);
            #pragma unroll
            for (int reg = 0; reg < 4; reg++) {
                const int trel = tr0 - reg;
                float bd = 0.f;
                if (trel != 1) {
                    const int ix = reg + (trel >= 2 ? 1 : 0);
                    ushort_t v;
                    if (ix == 0)      v = q4a.x;
                    else if (ix == 1) v = q4a.y;
                    else if (ix == 2) v = q4a.z;
                    else if (ix == 3) v = q4a.w;
                    else              v = b4;
                    bd = bf2f((short)v);
                }
                const float e = __expf((acc[tile][reg] + bd) * 0.125f);
                p[tile][reg] = e;
                lacc[reg] += e;
            }
        }
        // ---- P -> LDS (wave-private), PV with global V frags ----
        #pragma unroll
        for (int tile = 0; tile < 4; tile++)
            #pragma unroll
            for (int reg = 0; reg < 4; reg++)
                Ps[quad * 4 + reg][tile * 16 + col] = f2bf(p[tile][reg]);
        __asm__ volatile("s_waitcnt lgkmcnt(0)" ::: "memory");
        #pragma unroll
        for (int dt = 0; dt < 4; dt++) {
            #pragma unroll
            for (int ks = 0; ks < 2; ks++) {
                s8v pf = *(s8v*)&Ps[col][ks * 32 + quad * 8];
                Oacc[dt] = mfma16(pf, vfr[dt][ks], Oacc[dt]);
            }
        }

        // ---- write prefetched tile s+1 (no barrier needed: all reads of
        //      Ks/Res/Rb finished before [B]; visibility via next [A]) ----
        if (s < 31) {
            #pragma unroll
            for (int e = 0; e < 2; e++) {
                const int idx = t + e * 256;
                const int r   = idx >> 3;
                const int d8  = (idx & 7) * 8;
                *(s8v*)&Ks[r][d8] = pk[e];
                *(s8v*)&Res[(r + off) & 127][d8] = pr[e];
            }
            if (t < 64) Rb[(t + off) & 127] = prb;
            off = (off + 64) & 127;
        }
    }

    // ---- final l reduction (16 lanes per row) + epilogue ----
    #pragma unroll
    for (int reg = 0; reg < 4; reg++) {
        #pragma unroll
        for (int msk = 1; msk < 16; msk <<= 1)
            lacc[reg] += __shfl_xor(lacc[reg], msk, 64);
    }
    #pragma unroll
    for (int reg = 0; reg < 4; reg++) {
        const float inv = 1.f / lacc[reg];
        const int row = i0 + 16 * w + quad * 4 + reg;
        const size_t base = ((size_t)b * N + row) * HID + h * D;
        #pragma unroll
        for (int dt = 0; dt < 4; dt++)
            out[base + dt * 16 + col] = Oacc[dt][reg] * inv;
    }
}

// ---------------------------------------------------------------------------
extern "C" void kernel_launch(void* const* d_in, const int* in_sizes, int n_in,
                              void* d_out, int out_size, void* d_ws, size_t ws_size,
                              hipStream_t stream)
{
    (void)in_sizes; (void)n_in; (void)out_size; (void)ws_size;
    const float* hs   = (const float*)d_in[0];
    const float* remb = (const float*)d_in[1];
    const float* rwb  = (const float*)d_in[2];
    const float* rb   = (const float*)d_in[3];
    const float* Wq   = (const float*)d_in[4];
    const float* bq   = (const float*)d_in[5];
    const float* Wk   = (const float*)d_in[6];
    const float* bk   = (const float*)d_in[7];
    const float* Wv   = (const float*)d_in[8];
    const float* bv   = (const float*)d_in[9];
    float* out = (float*)d_out;

    ushort_t* Qb  = (ushort_t*)d_ws;
    ushort_t* Kb  = Qb + QKV_ELEMS;
    ushort_t* Vt  = Kb + QKV_ELEMS;
    ushort_t* reb = Vt + QKV_ELEMS;
    float*    rbt = (float*)(reb + H * N * D);
    ushort_t* hsb = (ushort_t*)(rbt + H * N);
    ushort_t* Wb  = hsb + (size_t)M * HID;

    convert_kernel<<<CVT_C3 / 256, 256, 0, stream>>>(
        hs, Wq, Wk, Wv, remb, rb, hsb, Wb, reb, rbt);
    qkv_mfma_kernel<<<dim3(M / 128, HID / 128, 3), 256, 0, stream>>>(
        hsb, Wb, bq, bk, bv, Qb, Kb, Vt);
    attn_mfma_kernel<<<dim3(N / 64, H, B), 256, 0, stream>>>(
        Qb, Kb, Vt, reb, rbt, rwb, out);
}